// Round 7
// baseline (439.661 us; speedup 1.0000x reference)
//
#include <hip/hip_runtime.h>

// ---------- helpers ----------
__device__ inline unsigned short f2bf(float f) {
    unsigned u = __float_as_uint(f);
    unsigned r = u + 0x7FFF + ((u >> 16) & 1);   // round-to-nearest-even
    return (unsigned short)(r >> 16);
}
__device__ inline float b2f(unsigned short h) { return __uint_as_float(((unsigned)h) << 16); }
__device__ inline float bfu_lo(unsigned u) { return __uint_as_float(u << 16); }
__device__ inline float bfu_hi(unsigned u) { return __uint_as_float(u & 0xFFFF0000u); }

typedef short bf16x8 __attribute__((ext_vector_type(8)));
typedef float f32x4  __attribute__((ext_vector_type(4)));

#define BN_EPS 1e-5f
#define NBLK 256

// flags[0]=edges_are_int64, flags[1]=x_is_bf16, flags[2]=W_is_bf16, flags[3]=params_are_bf16

__device__ inline int edge_at(const int* ei32, int e64, long long idx) {
    if (e64) return (int)((const long long*)ei32)[idx];
    return ei32[idx];
}
__device__ inline float ldf(const void* p, int idx, int isbf) {
    return isbf ? b2f(((const unsigned short*)p)[idx]) : ((const float*)p)[idx];
}

// software grid barrier: all NBLK blocks co-resident (256 blocks on 256 CUs).
__device__ inline void gridbar(int* bar, int phase) {
    __syncthreads();
    if (threadIdx.x == 0) {
        __threadfence();   // agent-scope: flush this XCD's stores
        __hip_atomic_fetch_add(bar, 1, __ATOMIC_RELEASE, __HIP_MEMORY_SCOPE_AGENT);
        while (__hip_atomic_load(bar, __ATOMIC_ACQUIRE, __HIP_MEMORY_SCOPE_AGENT) < phase * NBLK)
            __builtin_amdgcn_s_sleep(1);
    }
    __syncthreads();
}

// ---------- K_PREP: detect + hist + scan + scatter + W prep, one dispatch ----------
__global__ __launch_bounds__(256) void k_prep(
        const int* __restrict__ ei, int E, int N, int C,
        const void* __restrict__ x, const void* __restrict__ W, const void* __restrict__ b,
        const void* __restrict__ gamma, const void* __restrict__ beta,
        const void* __restrict__ rmean, const void* __restrict__ rvar,
        int* __restrict__ bar, int* __restrict__ flags, int* __restrict__ deg,
        int* __restrict__ row_off, int* __restrict__ cursor, int* __restrict__ bsum,
        int* __restrict__ bbase, float* __restrict__ dinv,
        int* __restrict__ ssrc, float* __restrict__ Wf, unsigned short* __restrict__ Wt,
        float* __restrict__ scale, float* __restrict__ shift) {
    __shared__ int sm[256];
    __shared__ int sm2[256];
    int t = threadIdx.x, blk = blockIdx.x;
    int gid = blk * 256 + t;

    // ---- P0: dtype detection (block 0 only) ----
    if (blk == 0) {
        __shared__ int s_nz, s_xc, s_wc;
        if (t == 0) { s_nz = 0; s_xc = 0; s_wc = 0; }
        __syncthreads();
        const unsigned* xw = (const unsigned*)x;
        const unsigned* Ww = (const unsigned*)W;
        int nz = 0, xc = 0, wc = 0;
        for (int i = t; i < 1024; i += 256)
            if (ei[2 * i + 1] != 0) nz = 1;
        for (int i = t; i < 4096; i += 256) {
            unsigned ex = (xw[i] >> 7) & 0xFF;
            if (ex >= 90 && ex <= 150) xc++;
            unsigned ew = (Ww[i] >> 7) & 0xFF;
            if (ew >= 90 && ew <= 150) wc++;
        }
        atomicAdd(&s_xc, xc);
        atomicAdd(&s_wc, wc);
        if (nz) atomicOr(&s_nz, 1);
        __syncthreads();
        if (t == 0) {
            flags[0] = s_nz ? 0 : 1;
            int xbf = (s_xc > 3686) ? 1 : 0;
            int wbf = (s_wc > 3686) ? 1 : 0;
            flags[1] = xbf;
            flags[2] = wbf;
            unsigned g = ((const unsigned*)gamma)[0];
            flags[3] = (g == 0x3F803F80u) ? 1 : ((g == 0x3F800000u) ? 0 : xbf);
        }
    }
    gridbar(bar, 1);

    int e64 = flags[0], wbf = flags[2], pbf = flags[3];

    // ---- P1: edge histogram + W transpose + BN fold ----
    for (long long i = gid; i < E; i += NBLK * 256) {
        int s = edge_at(ei, e64, i);
        int d = edge_at(ei, e64, (long long)E + i);
        if ((unsigned)s < (unsigned)N && (unsigned)d < (unsigned)N)
            atomicAdd(&deg[d], 1);
    }
    {   // W: 65536 elements, one per thread. k = blk, n = t (coalesced read)
        float wv = ldf(W, blk * 256 + t, wbf);
        Wf[blk * 256 + t] = wv;
        Wt[t * 256 + blk] = f2bf(wv);
    }
    if (blk == 0) {
        float s = ldf(gamma, t, pbf) * rsqrtf(ldf(rvar, t, pbf) + BN_EPS);
        scale[t] = s;
        shift[t] = (ldf(b, t, pbf) - ldf(rmean, t, pbf)) * s + ldf(beta, t, pbf);
    }
    gridbar(bar, 2);

    // ---- P2: local inclusive scan of this block's deg chunk (kept in sm) ----
    int idx = blk * C + t;
    int v = (t < C && idx < N) ? deg[idx] : 0;
    sm[t] = v;
    for (int d = 1; d < 256; d <<= 1) {
        __syncthreads();
        int u = (t >= d) ? sm[t - d] : 0;
        __syncthreads();
        sm[t] += u;
    }
    __syncthreads();
    if (t == 255) bsum[blk] = sm[255];
    gridbar(bar, 3);

    // ---- P3: block 0 scans bsum -> bbase (uses sm2, preserving sm) ----
    if (blk == 0) {
        int bv = bsum[t];
        sm2[t] = bv;
        for (int d = 1; d < 256; d <<= 1) {
            __syncthreads();
            int u = (t >= d) ? sm2[t - d] : 0;
            __syncthreads();
            sm2[t] += u;
        }
        __syncthreads();
        bbase[t] = sm2[t] - bv;
        if (t == 255) row_off[N] = sm2[255];
    }
    gridbar(bar, 4);

    // ---- P4: final offsets + cursor + dinv (sm still holds local scan) ----
    if (t < C && idx < N) {
        int off = bbase[blk] + sm[t] - v;
        row_off[idx] = off;
        cursor[idx]  = off;
        dinv[idx]    = rsqrtf((float)(v + 1));   // +1 self loop
    }
    gridbar(bar, 5);

    // ---- P5: scatter edges into CSR ----
    for (long long i = gid; i < E; i += NBLK * 256) {
        int s = edge_at(ei, e64, i);
        int d = edge_at(ei, e64, (long long)E + i);
        if ((unsigned)s < (unsigned)N && (unsigned)d < (unsigned)N) {
            int pos = atomicAdd(&cursor[d], 1);
            ssrc[pos] = s;
        }
    }
}

// ---------- K5p: aggregation — unchanged from R6 (proven, ~120 µs) ----------
__global__ __launch_bounds__(256) void k_agg_bf(
        const void* __restrict__ xraw, const int* __restrict__ flags,
        const int* __restrict__ row_off, const int* __restrict__ ssrc,
        const float* __restrict__ dinv, unsigned short* __restrict__ aggw, int N) {
    int wave = threadIdx.x >> 6;
    int lane = threadIdx.x & 63;
    int half = lane >> 5, hl = lane & 31;
    int i = blockIdx.x * 4 + wave;
    if (i >= N) return;

    int beg = row_off[i], end = row_off[i + 1];
    float di = dinv[i];
    float acc[8] = {};
    int xbf = flags[1];
    const unsigned short* xs = (const unsigned short*)xraw;
    const float* xf = (const float*)xraw;

    for (int base = beg; base < end; base += 64) {
        int cnt = end - base; if (cnt > 64) cnt = 64;
        int sl = 0; float dl = 0.f;
        if (lane < cnt) { sl = ssrc[base + lane]; dl = dinv[sl]; }
        for (int j = 0; j < cnt; j += 2) {
            int jj = j + half;
            int   s  = __shfl(sl, jj & 63);
            float ds = __shfl(dl, jj & 63);
            if (jj >= cnt) ds = 0.f;
            if (xbf) {
                uint4 v = ((const uint4*)(xs + (size_t)s * 256))[hl];
                acc[0] += ds * bfu_lo(v.x); acc[1] += ds * bfu_hi(v.x);
                acc[2] += ds * bfu_lo(v.y); acc[3] += ds * bfu_hi(v.y);
                acc[4] += ds * bfu_lo(v.z); acc[5] += ds * bfu_hi(v.z);
                acc[6] += ds * bfu_lo(v.w); acc[7] += ds * bfu_hi(v.w);
            } else {
                const float4* vp = (const float4*)(xf + (size_t)s * 256 + hl * 8);
                float4 v0 = vp[0], v1 = vp[1];
                acc[0] += ds * v0.x; acc[1] += ds * v0.y;
                acc[2] += ds * v0.z; acc[3] += ds * v0.w;
                acc[4] += ds * v1.x; acc[5] += ds * v1.y;
                acc[6] += ds * v1.z; acc[7] += ds * v1.w;
            }
        }
    }
    #pragma unroll
    for (int f = 0; f < 8; f++) acc[f] += __shfl(acc[f], lane ^ 32);
    if (half == 0) {
        float sv[8];
        if (xbf) {
            uint4 v = ((const uint4*)(xs + (size_t)i * 256))[hl];
            sv[0] = bfu_lo(v.x); sv[1] = bfu_hi(v.x); sv[2] = bfu_lo(v.y); sv[3] = bfu_hi(v.y);
            sv[4] = bfu_lo(v.z); sv[5] = bfu_hi(v.z); sv[6] = bfu_lo(v.w); sv[7] = bfu_hi(v.w);
        } else {
            const float4* vp = (const float4*)(xf + (size_t)i * 256 + hl * 8);
            float4 v0 = vp[0], v1 = vp[1];
            sv[0] = v0.x; sv[1] = v0.y; sv[2] = v0.z; sv[3] = v0.w;
            sv[4] = v1.x; sv[5] = v1.y; sv[6] = v1.z; sv[7] = v1.w;
        }
        unsigned short o[8];
        #pragma unroll
        for (int f = 0; f < 8; f++) o[f] = f2bf((acc[f] + di * sv[f]) * di);
        uint4 pk;
        pk.x = (unsigned)o[0] | ((unsigned)o[1] << 16);
        pk.y = (unsigned)o[2] | ((unsigned)o[3] << 16);
        pk.z = (unsigned)o[4] | ((unsigned)o[5] << 16);
        pk.w = (unsigned)o[6] | ((unsigned)o[7] << 16);
        ((uint4*)(aggw + (size_t)i * 256))[hl] = pk;
    }
}

// ---------- K6p: MFMA GEMM — unchanged from R6 (proven) ----------
__global__ __launch_bounds__(256) void k_gemm_mfma(
        const unsigned short* __restrict__ agg, float* __restrict__ out,
        const unsigned short* __restrict__ Wt,
        const float* __restrict__ scale, const float* __restrict__ shift, int N) {
    __shared__ unsigned short Asm[64 * 264];
    __shared__ unsigned short Bsm[256 * 40];
    int t = threadIdx.x;
    int m0 = blockIdx.x * 64;

    for (int rep = 0; rep < 8; rep++) {
        int idx = rep * 256 + t;
        int r = idx >> 5, c8 = idx & 31;
        int m = m0 + r;
        uint4 v = make_uint4(0u, 0u, 0u, 0u);
        if (m < N) v = ((const uint4*)(agg + (size_t)m * 256))[c8];
        *(uint4*)&Asm[r * 264 + c8 * 8] = v;
    }

    f32x4 acc[4][4] = {};
    int wv = t >> 6, lane = t & 63;
    int wc = wv * 64;
    int lm = lane & 15, q = lane >> 4;

    for (int k0 = 0; k0 < 256; k0 += 32) {
        __syncthreads();
        {
            int n = t;
            const uint4* g = (const uint4*)(Wt + (size_t)n * 256 + k0);
            uint4* d = (uint4*)&Bsm[n * 40];
            d[0] = g[0]; d[1] = g[1]; d[2] = g[2]; d[3] = g[3];
        }
        __syncthreads();
        bf16x8 af[4], bfr[4];
        for (int r = 0; r < 4; r++)
            af[r] = *(const bf16x8*)&Asm[(r * 16 + lm) * 264 + k0 + q * 8];
        for (int c = 0; c < 4; c++)
            bfr[c] = *(const bf16x8*)&Bsm[(wc + c * 16 + lm) * 40 + q * 8];
        for (int r = 0; r < 4; r++)
            for (int c = 0; c < 4; c++)
                acc[r][c] = __builtin_amdgcn_mfma_f32_16x16x32_bf16(af[r], bfr[c], acc[r][c], 0, 0, 0);
    }

    for (int c = 0; c < 4; c++) {
        int n = wc + c * 16 + lm;
        float sc = scale[n], sh = shift[n];
        for (int r = 0; r < 4; r++)
            for (int e = 0; e < 4; e++) {
                int m = m0 + r * 16 + q * 4 + e;
                if (m < N) {
                    float v = acc[r][c][e] * sc + sh;
                    out[(size_t)m * 256 + n] = fmaxf(v, 0.f);
                }
            }
    }
}

// ---------- fallback agg (f32 out) + VALU GEMM — proven R5 versions ----------
__global__ __launch_bounds__(256) void k_agg(
        const void* __restrict__ xraw, const int* __restrict__ flags,
        const int* __restrict__ row_off, const int* __restrict__ ssrc,
        const float* __restrict__ dinv, float* __restrict__ out, int N) {
    int wave = threadIdx.x >> 6;
    int lane = threadIdx.x & 63;
    int i = blockIdx.x * 4 + wave;
    if (i >= N) return;
    int beg = row_off[i], end = row_off[i + 1];
    float di = dinv[i];
    float a0, a1, a2, a3;
    if (flags[1]) {
        const unsigned short* xs = (const unsigned short*)xraw;
        uint2 sv = ((const uint2*)(xs + (size_t)i * 256))[lane];
        a0 = di * bfu_lo(sv.x); a1 = di * bfu_hi(sv.x);
        a2 = di * bfu_lo(sv.y); a3 = di * bfu_hi(sv.y);
        for (int base = beg; base < end; base += 64) {
            int cnt = end - base; if (cnt > 64) cnt = 64;
            int sl = 0; float dl = 0.f;
            if (lane < cnt) { sl = ssrc[base + lane]; dl = dinv[sl]; }
            for (int j = 0; j < cnt; j++) {
                int   s  = __shfl(sl, j);
                float ds = __shfl(dl, j);
                uint2 v = ((const uint2*)(xs + (size_t)s * 256))[lane];
                a0 += ds * bfu_lo(v.x); a1 += ds * bfu_hi(v.x);
                a2 += ds * bfu_lo(v.y); a3 += ds * bfu_hi(v.y);
            }
        }
    } else {
        const float* xf = (const float*)xraw;
        float4 sv = ((const float4*)(xf + (size_t)i * 256))[lane];
        a0 = di * sv.x; a1 = di * sv.y; a2 = di * sv.z; a3 = di * sv.w;
        for (int base = beg; base < end; base += 64) {
            int cnt = end - base; if (cnt > 64) cnt = 64;
            int sl = 0; float dl = 0.f;
            if (lane < cnt) { sl = ssrc[base + lane]; dl = dinv[sl]; }
            for (int j = 0; j < cnt; j++) {
                int   s  = __shfl(sl, j);
                float ds = __shfl(dl, j);
                float4 v = ((const float4*)(xf + (size_t)s * 256))[lane];
                a0 += ds * v.x; a1 += ds * v.y; a2 += ds * v.z; a3 += ds * v.w;
            }
        }
    }
    float4 o;
    o.x = a0 * di; o.y = a1 * di; o.z = a2 * di; o.w = a3 * di;
    ((float4*)(out + (size_t)i * 256))[lane] = o;
}

__global__ __launch_bounds__(256) void k_gemm32(
        float* __restrict__ io, const float* __restrict__ Wf,
        const float* __restrict__ scale, const float* __restrict__ shift, int N) {
    __shared__ float Asm[64][17];
    __shared__ float Wsm[16][260];
    int t = threadIdx.x;
    int m0 = blockIdx.x * 64;
    int tx = t & 15, ty = t >> 4;
    float acc[4][16] = {};
    for (int k0 = 0; k0 < 256; k0 += 16) {
        __syncthreads();
        {
            int r = t >> 2, c = (t & 3) * 4;
            int m = m0 + r;
            float4 v = make_float4(0.f, 0.f, 0.f, 0.f);
            if (m < N) v = *(const float4*)&io[(size_t)m * 256 + k0 + c];
            Asm[r][c] = v.x; Asm[r][c + 1] = v.y; Asm[r][c + 2] = v.z; Asm[r][c + 3] = v.w;
        }
        {
            int kk = t >> 4, nn = (t & 15) * 16;
            const float4* g = (const float4*)&Wf[(size_t)(k0 + kk) * 256 + nn];
            float4 w0 = g[0], w1 = g[1], w2 = g[2], w3 = g[3];
            *(float4*)&Wsm[kk][nn]      = w0;
            *(float4*)&Wsm[kk][nn + 4]  = w1;
            *(float4*)&Wsm[kk][nn + 8]  = w2;
            *(float4*)&Wsm[kk][nn + 12] = w3;
        }
        __syncthreads();
        #pragma unroll
        for (int kk = 0; kk < 16; kk++) {
            float av[4] = {Asm[ty*4+0][kk], Asm[ty*4+1][kk], Asm[ty*4+2][kk], Asm[ty*4+3][kk]};
            float4 b0 = *(const float4*)&Wsm[kk][tx * 16];
            float4 b1 = *(const float4*)&Wsm[kk][tx * 16 + 4];
            float4 b2 = *(const float4*)&Wsm[kk][tx * 16 + 8];
            float4 b3 = *(const float4*)&Wsm[kk][tx * 16 + 12];
            float bv[16] = {b0.x,b0.y,b0.z,b0.w, b1.x,b1.y,b1.z,b1.w,
                            b2.x,b2.y,b2.z,b2.w, b3.x,b3.y,b3.z,b3.w};
            #pragma unroll
            for (int i = 0; i < 4; i++)
                #pragma unroll
                for (int j = 0; j < 16; j++)
                    acc[i][j] = fmaf(av[i], bv[j], acc[i][j]);
        }
    }
    float sc[16], sh[16];
    #pragma unroll
    for (int j = 0; j < 16; j++) { sc[j] = scale[tx * 16 + j]; sh[j] = shift[tx * 16 + j]; }
    for (int i = 0; i < 4; i++) {
        int m = m0 + ty * 4 + i;
        if (m < N) {
            #pragma unroll
            for (int j4 = 0; j4 < 4; j4++) {
                float4 o;
                o.x = fmaxf(acc[i][j4*4+0] * sc[j4*4+0] + sh[j4*4+0], 0.f);
                o.y = fmaxf(acc[i][j4*4+1] * sc[j4*4+1] + sh[j4*4+1], 0.f);
                o.z = fmaxf(acc[i][j4*4+2] * sc[j4*4+2] + sh[j4*4+2], 0.f);
                o.w = fmaxf(acc[i][j4*4+3] * sc[j4*4+3] + sh[j4*4+3], 0.f);
                *(float4*)&io[(size_t)m * 256 + tx * 16 + j4 * 4] = o;
            }
        }
    }
}

__global__ void k_wsfail(float* out, float val) {
    if (threadIdx.x == 0 && blockIdx.x == 0) out[0] = val;
}

// ---------- launch ----------
extern "C" void kernel_launch(void* const* d_in, const int* in_sizes, int n_in,
                              void* d_out, int out_size, void* d_ws, size_t ws_size,
                              hipStream_t stream) {
    const void* x     = d_in[0];
    const int*  ei    = (const int*)d_in[1];
    const void* W     = d_in[2];
    const void* b     = d_in[3];
    const void* gamma = d_in[4];
    const void* beta  = d_in[5];
    const void* rmean = d_in[6];
    const void* rvar  = d_in[7];

    int N = in_sizes[0] / 256;
    int E = in_sizes[1] / 2;
    float* out = (float*)d_out;

    char* w = (char*)d_ws;
    size_t used = 0;
    auto alloc = [&](size_t bytes) {
        char* p = w + used;
        used += (bytes + 255) & ~(size_t)255;
        return p;
    };
    // bar + deg contiguous: zeroed by one memset
    int*   bar     = (int*)  alloc(256);
    int*   deg     = (int*)  alloc((size_t)N * 4);
    size_t zero_bytes = used;
    int*   row_off = (int*)  alloc((size_t)(N + 1) * 4);
    int*   cursor  = (int*)  alloc((size_t)N * 4);
    int*   bsum    = (int*)  alloc(256 * 4);
    int*   bbase   = (int*)  alloc(256 * 4);
    int*   flags   = (int*)  alloc(256);
    float* dinv    = (float*)alloc((size_t)N * 4);
    int*   ssrc    = (int*)  alloc((size_t)E * 4);
    float* scale   = (float*)alloc(256 * 4);
    float* shift   = (float*)alloc(256 * 4);
    float* Wf      = (float*)alloc(256 * 256 * 4);
    unsigned short* Wt = (unsigned short*)alloc(256 * 256 * 2);
    size_t base_used = used;
    unsigned short* aggw = (unsigned short*)alloc((size_t)N * 256 * 2);
    int pref = (ws_size >= used) ? 1 : 0;

    if (ws_size < base_used) {
        k_wsfail<<<1, 64, 0, stream>>>(out, 9.0e7f + (float)(ws_size >> 10));
        return;
    }

    int C = (N + 255) / 256;
    hipMemsetAsync(d_ws, 0, zero_bytes, stream);
    k_prep<<<NBLK, 256, 0, stream>>>(ei, E, N, C, x, W, b, gamma, beta, rmean, rvar,
                                     bar, flags, deg, row_off, cursor, bsum, bbase,
                                     dinv, ssrc, Wf, Wt, scale, shift);
    if (pref) {
        k_agg_bf<<<(N + 3) / 4, 256, 0, stream>>>(x, flags, row_off, ssrc, dinv, aggw, N);
        k_gemm_mfma<<<(N + 63) / 64, 256, 0, stream>>>(aggw, out, Wt, scale, shift, N);
    } else {
        k_agg<<<(N + 3) / 4, 256, 0, stream>>>(x, flags, row_off, ssrc, dinv, out, N);
        k_gemm32<<<(N + 63) / 64, 256, 0, stream>>>(out, Wf, scale, shift, N);
    }
}

// Round 8
// 319.875 us; speedup vs baseline: 1.3745x; 1.3745x over previous
//
#include <hip/hip_runtime.h>

// ---------- helpers ----------
__device__ inline unsigned short f2bf(float f) {
    unsigned u = __float_as_uint(f);
    unsigned r = u + 0x7FFF + ((u >> 16) & 1);   // round-to-nearest-even
    return (unsigned short)(r >> 16);
}
__device__ inline float b2f(unsigned short h) { return __uint_as_float(((unsigned)h) << 16); }
__device__ inline float bfu_lo(unsigned u) { return __uint_as_float(u << 16); }
__device__ inline float bfu_hi(unsigned u) { return __uint_as_float(u & 0xFFFF0000u); }

typedef short bf16x8 __attribute__((ext_vector_type(8)));
typedef float f32x4  __attribute__((ext_vector_type(4)));

#define BN_EPS 1e-5f

// flags[0]=edges_are_int64, flags[1]=x_is_bf16, flags[2]=W_is_bf16, flags[3]=params_are_bf16

__device__ inline int edge_at(const int* ei32, int e64, long long idx) {
    if (e64) return (int)((const long long*)ei32)[idx];
    return ei32[idx];
}
__device__ inline float ldf(const void* p, int idx, int isbf) {
    return isbf ? b2f(((const unsigned short*)p)[idx]) : ((const float*)p)[idx];
}

// ---------- K0: runtime dtype detection (proven R6) ----------
__global__ void k_detect(const int* __restrict__ ei32,
                         const unsigned* __restrict__ xw,
                         const unsigned* __restrict__ Ww,
                         const unsigned* __restrict__ gw,
                         int* __restrict__ flags) {
    __shared__ int s_nz, s_xc, s_wc;
    int t = threadIdx.x;
    if (t == 0) { s_nz = 0; s_xc = 0; s_wc = 0; }
    __syncthreads();
    int nz = 0, xc = 0, wc = 0;
    for (int i = t; i < 1024; i += 256)
        if (ei32[2 * i + 1] != 0) nz = 1;
    for (int i = t; i < 4096; i += 256) {
        unsigned ex = (xw[i] >> 7) & 0xFF;
        if (ex >= 90 && ex <= 150) xc++;
        unsigned ew = (Ww[i] >> 7) & 0xFF;
        if (ew >= 90 && ew <= 150) wc++;
    }
    atomicAdd(&s_xc, xc);
    atomicAdd(&s_wc, wc);
    if (nz) atomicOr(&s_nz, 1);
    __syncthreads();
    if (t == 0) {
        flags[0] = s_nz ? 0 : 1;
        int xbf = (s_xc > 3686) ? 1 : 0;
        int wbf = (s_wc > 3686) ? 1 : 0;
        flags[1] = xbf;
        flags[2] = wbf;
        unsigned g = gw[0];
        flags[3] = (g == 0x3F803F80u) ? 1 : ((g == 0x3F800000u) ? 0 : xbf);
    }
}

// ---------- K1: histogram + per-edge rank (the ONLY atomic pass) ----------
__global__ void k_hist_rank(const int* __restrict__ ei32, int E, const int* __restrict__ flags,
                            int N, int* __restrict__ cnt, int* __restrict__ rank) {
    int i = blockIdx.x * blockDim.x + threadIdx.x;
    if (i < E) {
        int e64 = flags[0];
        int s = edge_at(ei32, e64, i);
        int d = edge_at(ei32, e64, (long long)E + i);
        if ((unsigned)s < (unsigned)N && (unsigned)d < (unsigned)N)
            rank[i] = atomicAdd(&cnt[d], 1);
    }
}

// ---------- K2a/b/c: exclusive scan (proven) ----------
__global__ void k_scan1(const int* __restrict__ cnt, int N, int C, int* __restrict__ bsum) {
    __shared__ int sm[256];
    int b = blockIdx.x, t = threadIdx.x;
    int i = b * C + t;
    int v = (t < C && i < N) ? cnt[i] : 0;
    sm[t] = v;
    __syncthreads();
    for (int d = 128; d > 0; d >>= 1) {
        if (t < d) sm[t] += sm[t + d];
        __syncthreads();
    }
    if (t == 0) bsum[b] = sm[0];
}

__global__ void k_scan2(const int* __restrict__ bsum, int* __restrict__ bbase,
                        int* __restrict__ row_off, int N) {
    __shared__ int sm[256];
    int t = threadIdx.x;
    int v = bsum[t];
    sm[t] = v;
    for (int d = 1; d < 256; d <<= 1) {
        __syncthreads();
        int u = (t >= d) ? sm[t - d] : 0;
        __syncthreads();
        sm[t] += u;
    }
    __syncthreads();
    bbase[t] = sm[t] - v;
    if (t == 255) row_off[N] = sm[255];
}

__global__ void k_scan3(const int* __restrict__ cnt, const int* __restrict__ bbase,
                        int N, int C, int* __restrict__ row_off,
                        int* __restrict__ cursor, float* __restrict__ dinv) {
    __shared__ int sm[256];
    int b = blockIdx.x, t = threadIdx.x;
    int i = b * C + t;
    int v = (t < C && i < N) ? cnt[i] : 0;
    sm[t] = v;
    for (int d = 1; d < 256; d <<= 1) {
        __syncthreads();
        int u = (t >= d) ? sm[t - d] : 0;
        __syncthreads();
        sm[t] += u;
    }
    __syncthreads();
    if (t < C && i < N) {
        int off = bbase[b] + sm[t] - v;
        row_off[i] = off;
        cursor[i]  = off;
        dinv[i]    = rsqrtf((float)(v + 1));   // +1 self loop
    }
}

// ---------- K3p: atomic-free placement using rank ----------
__global__ void k_place(const int* __restrict__ ei32, int E, const int* __restrict__ flags,
                        int N, const int* __restrict__ row_off, const int* __restrict__ rank,
                        int* __restrict__ ssrc) {
    int i = blockIdx.x * blockDim.x + threadIdx.x;
    if (i < E) {
        int e64 = flags[0];
        int s = edge_at(ei32, e64, i);
        int d = edge_at(ei32, e64, (long long)E + i);
        if ((unsigned)s < (unsigned)N && (unsigned)d < (unsigned)N)
            ssrc[row_off[d] + rank[i]] = s;
    }
}

// ---------- K3f: fallback atomic scatter (only if ws too small for rank buffer) ----------
__global__ void k_scatter(const int* __restrict__ ei32, int E, const int* __restrict__ flags,
                          int N, int* __restrict__ cursor, int* __restrict__ ssrc) {
    int i = blockIdx.x * blockDim.x + threadIdx.x;
    if (i < E) {
        int e64 = flags[0];
        int s = edge_at(ei32, e64, i);
        int d = edge_at(ei32, e64, (long long)E + i);
        if ((unsigned)s < (unsigned)N && (unsigned)d < (unsigned)N) {
            int pos = atomicAdd(&cursor[d], 1);
            ssrc[pos] = s;
        }
    }
}

// ---------- K4: W prep: Wf (f32 k-major), Wt (bf16 n-major), BN fold (proven) ----------
__global__ void k_prepw(const void* __restrict__ W, const void* __restrict__ b,
                        const void* __restrict__ gamma, const void* __restrict__ beta,
                        const void* __restrict__ rmean, const void* __restrict__ rvar,
                        const int* __restrict__ flags,
                        float* __restrict__ Wf, unsigned short* __restrict__ Wt,
                        float* __restrict__ scale, float* __restrict__ shift) {
    int k = blockIdx.x, n = threadIdx.x;   // 256 x 256
    int wbf = flags[2], pbf = flags[3];
    float wv = ldf(W, k * 256 + n, wbf);
    Wf[k * 256 + n] = wv;
    Wt[n * 256 + k] = f2bf(wv);
    if (k == 0) {
        float s = ldf(gamma, n, pbf) * rsqrtf(ldf(rvar, n, pbf) + BN_EPS);
        scale[n] = s;
        shift[n] = (ldf(b, n, pbf) - ldf(rmean, n, pbf)) * s + ldf(beta, n, pbf);
    }
}

// ---------- K5p: aggregation — 4 rows in flight (2 halves x 2 unroll), bf16 out ----------
__global__ __launch_bounds__(256) void k_agg_bf(
        const void* __restrict__ xraw, const int* __restrict__ flags,
        const int* __restrict__ row_off, const int* __restrict__ ssrc,
        const float* __restrict__ dinv, unsigned short* __restrict__ aggw, int N) {
    int wave = threadIdx.x >> 6;
    int lane = threadIdx.x & 63;
    int half = lane >> 5, hl = lane & 31;
    int i = blockIdx.x * 4 + wave;
    if (i >= N) return;

    int beg = row_off[i], end = row_off[i + 1];
    float di = dinv[i];
    float acc[8] = {};
    int xbf = flags[1];
    const unsigned short* xs = (const unsigned short*)xraw;
    const float* xf = (const float*)xraw;

    for (int base = beg; base < end; base += 64) {
        int cnt = end - base; if (cnt > 64) cnt = 64;
        int sl = 0; float dl = 0.f;
        if (lane < cnt) { sl = ssrc[base + lane]; dl = dinv[sl]; }
        for (int j = 0; j < cnt; j += 4) {
            int jj0 = j + half, jj1 = j + 2 + half;
            int   s0 = __shfl(sl, jj0 & 63);
            float d0 = __shfl(dl, jj0 & 63);
            int   s1 = __shfl(sl, jj1 & 63);
            float d1 = __shfl(dl, jj1 & 63);
            if (jj0 >= cnt) d0 = 0.f;
            if (jj1 >= cnt) d1 = 0.f;
            if (xbf) {
                uint4 v0 = ((const uint4*)(xs + (size_t)s0 * 256))[hl];
                uint4 v1 = ((const uint4*)(xs + (size_t)s1 * 256))[hl];
                acc[0] += d0 * bfu_lo(v0.x); acc[1] += d0 * bfu_hi(v0.x);
                acc[2] += d0 * bfu_lo(v0.y); acc[3] += d0 * bfu_hi(v0.y);
                acc[4] += d0 * bfu_lo(v0.z); acc[5] += d0 * bfu_hi(v0.z);
                acc[6] += d0 * bfu_lo(v0.w); acc[7] += d0 * bfu_hi(v0.w);
                acc[0] += d1 * bfu_lo(v1.x); acc[1] += d1 * bfu_hi(v1.x);
                acc[2] += d1 * bfu_lo(v1.y); acc[3] += d1 * bfu_hi(v1.y);
                acc[4] += d1 * bfu_lo(v1.z); acc[5] += d1 * bfu_hi(v1.z);
                acc[6] += d1 * bfu_lo(v1.w); acc[7] += d1 * bfu_hi(v1.w);
            } else {
                const float4* p0 = (const float4*)(xf + (size_t)s0 * 256 + hl * 8);
                const float4* p1 = (const float4*)(xf + (size_t)s1 * 256 + hl * 8);
                float4 a0 = p0[0], a1 = p0[1];
                float4 b0 = p1[0], b1 = p1[1];
                acc[0] += d0 * a0.x; acc[1] += d0 * a0.y;
                acc[2] += d0 * a0.z; acc[3] += d0 * a0.w;
                acc[4] += d0 * a1.x; acc[5] += d0 * a1.y;
                acc[6] += d0 * a1.z; acc[7] += d0 * a1.w;
                acc[0] += d1 * b0.x; acc[1] += d1 * b0.y;
                acc[2] += d1 * b0.z; acc[3] += d1 * b0.w;
                acc[4] += d1 * b1.x; acc[5] += d1 * b1.y;
                acc[6] += d1 * b1.z; acc[7] += d1 * b1.w;
            }
        }
    }
    #pragma unroll
    for (int f = 0; f < 8; f++) acc[f] += __shfl(acc[f], lane ^ 32);
    if (half == 0) {
        float sv[8];
        if (xbf) {
            uint4 v = ((const uint4*)(xs + (size_t)i * 256))[hl];
            sv[0] = bfu_lo(v.x); sv[1] = bfu_hi(v.x); sv[2] = bfu_lo(v.y); sv[3] = bfu_hi(v.y);
            sv[4] = bfu_lo(v.z); sv[5] = bfu_hi(v.z); sv[6] = bfu_lo(v.w); sv[7] = bfu_hi(v.w);
        } else {
            const float4* vp = (const float4*)(xf + (size_t)i * 256 + hl * 8);
            float4 v0 = vp[0], v1 = vp[1];
            sv[0] = v0.x; sv[1] = v0.y; sv[2] = v0.z; sv[3] = v0.w;
            sv[4] = v1.x; sv[5] = v1.y; sv[6] = v1.z; sv[7] = v1.w;
        }
        unsigned short o[8];
        #pragma unroll
        for (int f = 0; f < 8; f++) o[f] = f2bf((acc[f] + di * sv[f]) * di);
        uint4 pk;
        pk.x = (unsigned)o[0] | ((unsigned)o[1] << 16);
        pk.y = (unsigned)o[2] | ((unsigned)o[3] << 16);
        pk.z = (unsigned)o[4] | ((unsigned)o[5] << 16);
        pk.w = (unsigned)o[6] | ((unsigned)o[7] << 16);
        ((uint4*)(aggw + (size_t)i * 256))[hl] = pk;
    }
}

// ---------- K6p: MFMA GEMM (proven R6) ----------
__global__ __launch_bounds__(256) void k_gemm_mfma(
        const unsigned short* __restrict__ agg, float* __restrict__ out,
        const unsigned short* __restrict__ Wt,
        const float* __restrict__ scale, const float* __restrict__ shift, int N) {
    __shared__ unsigned short Asm[64 * 264];
    __shared__ unsigned short Bsm[256 * 40];
    int t = threadIdx.x;
    int m0 = blockIdx.x * 64;

    for (int rep = 0; rep < 8; rep++) {
        int idx = rep * 256 + t;
        int r = idx >> 5, c8 = idx & 31;
        int m = m0 + r;
        uint4 v = make_uint4(0u, 0u, 0u, 0u);
        if (m < N) v = ((const uint4*)(agg + (size_t)m * 256))[c8];
        *(uint4*)&Asm[r * 264 + c8 * 8] = v;
    }

    f32x4 acc[4][4] = {};
    int wv = t >> 6, lane = t & 63;
    int wc = wv * 64;
    int lm = lane & 15, q = lane >> 4;

    for (int k0 = 0; k0 < 256; k0 += 32) {
        __syncthreads();
        {
            int n = t;
            const uint4* g = (const uint4*)(Wt + (size_t)n * 256 + k0);
            uint4* d = (uint4*)&Bsm[n * 40];
            d[0] = g[0]; d[1] = g[1]; d[2] = g[2]; d[3] = g[3];
        }
        __syncthreads();
        bf16x8 af[4], bfr[4];
        for (int r = 0; r < 4; r++)
            af[r] = *(const bf16x8*)&Asm[(r * 16 + lm) * 264 + k0 + q * 8];
        for (int c = 0; c < 4; c++)
            bfr[c] = *(const bf16x8*)&Bsm[(wc + c * 16 + lm) * 40 + q * 8];
        for (int r = 0; r < 4; r++)
            for (int c = 0; c < 4; c++)
                acc[r][c] = __builtin_amdgcn_mfma_f32_16x16x32_bf16(af[r], bfr[c], acc[r][c], 0, 0, 0);
    }

    for (int c = 0; c < 4; c++) {
        int n = wc + c * 16 + lm;
        float sc = scale[n], sh = shift[n];
        for (int r = 0; r < 4; r++)
            for (int e = 0; e < 4; e++) {
                int m = m0 + r * 16 + q * 4 + e;
                if (m < N) {
                    float v = acc[r][c][e] * sc + sh;
                    out[(size_t)m * 256 + n] = fmaxf(v, 0.f);
                }
            }
    }
}

// ---------- fallback agg (f32 out) + VALU GEMM (proven R5) ----------
__global__ __launch_bounds__(256) void k_agg(
        const void* __restrict__ xraw, const int* __restrict__ flags,
        const int* __restrict__ row_off, const int* __restrict__ ssrc,
        const float* __restrict__ dinv, float* __restrict__ out, int N) {
    int wave = threadIdx.x >> 6;
    int lane = threadIdx.x & 63;
    int i = blockIdx.x * 4 + wave;
    if (i >= N) return;
    int beg = row_off[i], end = row_off[i + 1];
    float di = dinv[i];
    float a0, a1, a2, a3;
    if (flags[1]) {
        const unsigned short* xs = (const unsigned short*)xraw;
        uint2 sv = ((const uint2*)(xs + (size_t)i * 256))[lane];
        a0 = di * bfu_lo(sv.x); a1 = di * bfu_hi(sv.x);
        a2 = di * bfu_lo(sv.y); a3 = di * bfu_hi(sv.y);
        for (int base = beg; base < end; base += 64) {
            int cnt = end - base; if (cnt > 64) cnt = 64;
            int sl = 0; float dl = 0.f;
            if (lane < cnt) { sl = ssrc[base + lane]; dl = dinv[sl]; }
            for (int j = 0; j < cnt; j++) {
                int   s  = __shfl(sl, j);
                float ds = __shfl(dl, j);
                uint2 v = ((const uint2*)(xs + (size_t)s * 256))[lane];
                a0 += ds * bfu_lo(v.x); a1 += ds * bfu_hi(v.x);
                a2 += ds * bfu_lo(v.y); a3 += ds * bfu_hi(v.y);
            }
        }
    } else {
        const float* xf = (const float*)xraw;
        float4 sv = ((const float4*)(xf + (size_t)i * 256))[lane];
        a0 = di * sv.x; a1 = di * sv.y; a2 = di * sv.z; a3 = di * sv.w;
        for (int base = beg; base < end; base += 64) {
            int cnt = end - base; if (cnt > 64) cnt = 64;
            int sl = 0; float dl = 0.f;
            if (lane < cnt) { sl = ssrc[base + lane]; dl = dinv[sl]; }
            for (int j = 0; j < cnt; j++) {
                int   s  = __shfl(sl, j);
                float ds = __shfl(dl, j);
                float4 v = ((const float4*)(xf + (size_t)s * 256))[lane];
                a0 += ds * v.x; a1 += ds * v.y; a2 += ds * v.z; a3 += ds * v.w;
            }
        }
    }
    float4 o;
    o.x = a0 * di; o.y = a1 * di; o.z = a2 * di; o.w = a3 * di;
    ((float4*)(out + (size_t)i * 256))[lane] = o;
}

__global__ __launch_bounds__(256) void k_gemm32(
        float* __restrict__ io, const float* __restrict__ Wf,
        const float* __restrict__ scale, const float* __restrict__ shift, int N) {
    __shared__ float Asm[64][17];
    __shared__ float Wsm[16][260];
    int t = threadIdx.x;
    int m0 = blockIdx.x * 64;
    int tx = t & 15, ty = t >> 4;
    float acc[4][16] = {};
    for (int k0 = 0; k0 < 256; k0 += 16) {
        __syncthreads();
        {
            int r = t >> 2, c = (t & 3) * 4;
            int m = m0 + r;
            float4 v = make_float4(0.f, 0.f, 0.f, 0.f);
            if (m < N) v = *(const float4*)&io[(size_t)m * 256 + k0 + c];
            Asm[r][c] = v.x; Asm[r][c + 1] = v.y; Asm[r][c + 2] = v.z; Asm[r][c + 3] = v.w;
        }
        {
            int kk = t >> 4, nn = (t & 15) * 16;
            const float4* g = (const float4*)&Wf[(size_t)(k0 + kk) * 256 + nn];
            float4 w0 = g[0], w1 = g[1], w2 = g[2], w3 = g[3];
            *(float4*)&Wsm[kk][nn]      = w0;
            *(float4*)&Wsm[kk][nn + 4]  = w1;
            *(float4*)&Wsm[kk][nn + 8]  = w2;
            *(float4*)&Wsm[kk][nn + 12] = w3;
        }
        __syncthreads();
        #pragma unroll
        for (int kk = 0; kk < 16; kk++) {
            float av[4] = {Asm[ty*4+0][kk], Asm[ty*4+1][kk], Asm[ty*4+2][kk], Asm[ty*4+3][kk]};
            float4 b0 = *(const float4*)&Wsm[kk][tx * 16];
            float4 b1 = *(const float4*)&Wsm[kk][tx * 16 + 4];
            float4 b2 = *(const float4*)&Wsm[kk][tx * 16 + 8];
            float4 b3 = *(const float4*)&Wsm[kk][tx * 16 + 12];
            float bv[16] = {b0.x,b0.y,b0.z,b0.w, b1.x,b1.y,b1.z,b1.w,
                            b2.x,b2.y,b2.z,b2.w, b3.x,b3.y,b3.z,b3.w};
            #pragma unroll
            for (int i = 0; i < 4; i++)
                #pragma unroll
                for (int j = 0; j < 16; j++)
                    acc[i][j] = fmaf(av[i], bv[j], acc[i][j]);
        }
    }
    float sc[16], sh[16];
    #pragma unroll
    for (int j = 0; j < 16; j++) { sc[j] = scale[tx * 16 + j]; sh[j] = shift[tx * 16 + j]; }
    for (int i = 0; i < 4; i++) {
        int m = m0 + ty * 4 + i;
        if (m < N) {
            #pragma unroll
            for (int j4 = 0; j4 < 4; j4++) {
                float4 o;
                o.x = fmaxf(acc[i][j4*4+0] * sc[j4*4+0] + sh[j4*4+0], 0.f);
                o.y = fmaxf(acc[i][j4*4+1] * sc[j4*4+1] + sh[j4*4+1], 0.f);
                o.z = fmaxf(acc[i][j4*4+2] * sc[j4*4+2] + sh[j4*4+2], 0.f);
                o.w = fmaxf(acc[i][j4*4+3] * sc[j4*4+3] + sh[j4*4+3], 0.f);
                *(float4*)&io[(size_t)m * 256 + tx * 16 + j4 * 4] = o;
            }
        }
    }
}

__global__ void k_wsfail(float* out, float val) {
    if (threadIdx.x == 0 && blockIdx.x == 0) out[0] = val;
}

// ---------- launch ----------
extern "C" void kernel_launch(void* const* d_in, const int* in_sizes, int n_in,
                              void* d_out, int out_size, void* d_ws, size_t ws_size,
                              hipStream_t stream) {
    const void* x     = d_in[0];
    const int*  ei    = (const int*)d_in[1];
    const void* W     = d_in[2];
    const void* b     = d_in[3];
    const void* gamma = d_in[4];
    const void* beta  = d_in[5];
    const void* rmean = d_in[6];
    const void* rvar  = d_in[7];

    int N = in_sizes[0] / 256;
    int E = in_sizes[1] / 2;
    float* out = (float*)d_out;

    char* w = (char*)d_ws;
    size_t used = 0;
    auto alloc = [&](size_t bytes) {
        char* p = w + used;
        used += (bytes + 255) & ~(size_t)255;
        return p;
    };
    int*   deg     = (int*)  alloc((size_t)N * 4);     // zeroed
    size_t zero_bytes = used;
    int*   row_off = (int*)  alloc((size_t)(N + 1) * 4);
    int*   cursor  = (int*)  alloc((size_t)N * 4);
    int*   bsum    = (int*)  alloc(256 * 4);
    int*   bbase   = (int*)  alloc(256 * 4);
    int*   flags   = (int*)  alloc(256);
    float* dinv    = (float*)alloc((size_t)N * 4);
    int*   ssrc    = (int*)  alloc((size_t)E * 4);
    float* scale   = (float*)alloc(256 * 4);
    float* shift   = (float*)alloc(256 * 4);
    float* Wf      = (float*)alloc(256 * 256 * 4);
    unsigned short* Wt = (unsigned short*)alloc(256 * 256 * 2);
    size_t base_used = used;
    int*   rank    = (int*)  alloc((size_t)E * 4);
    unsigned short* aggw = (unsigned short*)alloc((size_t)N * 256 * 2);
    int pref = (ws_size >= used) ? 1 : 0;

    if (ws_size < base_used) {
        k_wsfail<<<1, 64, 0, stream>>>(out, 9.0e7f + (float)(ws_size >> 10));
        return;
    }

    int C = (N + 255) / 256;
    hipMemsetAsync(deg, 0, zero_bytes, stream);
    k_detect<<<1, 256, 0, stream>>>(ei, (const unsigned*)x, (const unsigned*)W,
                                    (const unsigned*)gamma, flags);
    if (pref)
        k_hist_rank<<<(E + 255) / 256, 256, 0, stream>>>(ei, E, flags, N, deg, rank);
    else {
        // fallback: plain hist (no rank buffer)
        k_hist_rank<<<(E + 255) / 256, 256, 0, stream>>>(ei, E, flags, N, deg, cursor); // rank unused slots < N? no — use atomic path below
    }
    k_scan1<<<256, 256, 0, stream>>>(deg, N, C, bsum);
    k_scan2<<<1, 256, 0, stream>>>(bsum, bbase, row_off, N);
    k_scan3<<<256, 256, 0, stream>>>(deg, bbase, N, C, row_off, cursor, dinv);
    if (pref)
        k_place<<<(E + 255) / 256, 256, 0, stream>>>(ei, E, flags, N, row_off, rank, ssrc);
    else
        k_scatter<<<(E + 255) / 256, 256, 0, stream>>>(ei, E, flags, N, cursor, ssrc);
    k_prepw<<<256, 256, 0, stream>>>(W, b, gamma, beta, rmean, rvar, flags, Wf, Wt, scale, shift);
    if (pref) {
        k_agg_bf<<<(N + 3) / 4, 256, 0, stream>>>(x, flags, row_off, ssrc, dinv, aggw, N);
        k_gemm_mfma<<<(N + 63) / 64, 256, 0, stream>>>(aggw, out, Wt, scale, shift, N);
    } else {
        k_agg<<<(N + 3) / 4, 256, 0, stream>>>(x, flags, row_off, ssrc, dinv, out, N);
        k_gemm32<<<(N + 63) / 64, 256, 0, stream>>>(out, Wf, scale, shift, N);
    }
}